// Round 14
// baseline (194.023 us; speedup 1.0000x reference)
//
#include <hip/hip_runtime.h>
#include <cstdint>

typedef unsigned int u32;
typedef unsigned short u16;

#define N_NODES 100000
#define N_EDGES 3200000
#define F_IN 128
#define DIM 10
#define QB 16            // bf16 elems per padded q row -> 32B
#define B_GRAPHS 1000
#define FRONT_T 512      // threads per k_front block (r11-proven)
#define NBLK_N 196       // ceil(N/512) gemm blocks

// r13 static layout (183.0us passing) + r14: k_lay1 drops the 18KB lrec
// stage (histogram from global runs; scatter re-reads them cache-hot) and
// replaces the 18-barrier 512-scan with k_front's 2-barrier wave scan.
// LDS 40.4->21.6KB => 4 blocks/CU (was 3): lay1 was latency-bound at 44%
// occupancy / 1.48 TB/s achieved.
#define SHIFTC 7
#define NBINS 128        // dst & 127 within a bucket
#define NCB 782          // ceil(N/128)
#define CAPC 4608        // slots/bucket: mean 4092 + 8 sigma
#define CHUNK_C 8192     // edges per bucketing block
#define NBLK_C 391       // ceil(E/CHUNK_C)
#define SEGW 129         // segment-start words per bucket (NBINS+1)
#define TW (NCB + 1)     // segt row width (783)

__device__ __forceinline__ u16 f2b(float f) {           // f32 -> bf16 (RNE)
  union { float f; u32 i; } c; c.f = f;
  u32 r = c.i + 0x7FFFu + ((c.i >> 16) & 1u);
  return (u16)(r >> 16);
}
__device__ __forceinline__ float bl(u32 u) {            // low bf16 -> f32
  union { u32 i; float f; } c; c.i = u << 16; return c.f;
}
__device__ __forceinline__ float bh(u32 u) {            // high bf16 -> f32
  union { u32 i; float f; } c; c.i = u & 0xFFFF0000u; return c.f;
}

// ---- gemm1 body: 1 thread/node (512/block), wave-uniform W indexing ----
__device__ __forceinline__ void gemm_body(
    int bid, int tid,
    const float* __restrict__ x, const float* __restrict__ W,
    float* __restrict__ p1, u16* __restrict__ q1b)
{
  int i = bid * FRONT_T + tid;
  if (i >= N_NODES) return;
  const float4* __restrict__ xr = (const float4*)(x + (size_t)i * F_IN);
  float ap[DIM], aq[DIM];
  #pragma unroll
  for (int j = 0; j < DIM; ++j) { ap[j] = 0.f; aq[j] = 0.f; }
  #pragma unroll 4
  for (int k4 = 0; k4 < F_IN / 4; ++k4) {
    float4 v = xr[k4];
    const float* __restrict__ w0 = W + (k4 * 4) * DIM;
    const float* __restrict__ w1 = W + (F_IN + k4 * 4) * DIM;
    #pragma unroll
    for (int j = 0; j < DIM; ++j) {
      ap[j] += v.x * w0[j] + v.y * w0[DIM + j] + v.z * w0[2 * DIM + j] + v.w * w0[3 * DIM + j];
      aq[j] += v.x * w1[j] + v.y * w1[DIM + j] + v.z * w1[2 * DIM + j] + v.w * w1[3 * DIM + j];
    }
  }
  float* pr = p1 + (size_t)i * DIM;
  #pragma unroll
  for (int j = 0; j < DIM; ++j) pr[j] = ap[j];
  u32* qr = (u32*)(q1b + (size_t)i * QB);
  uint4 v0; u32 v1;
  v0.x = (u32)f2b(aq[0]) | ((u32)f2b(aq[1]) << 16);
  v0.y = (u32)f2b(aq[2]) | ((u32)f2b(aq[3]) << 16);
  v0.z = (u32)f2b(aq[4]) | ((u32)f2b(aq[5]) << 16);
  v0.w = (u32)f2b(aq[6]) | ((u32)f2b(aq[7]) << 16);
  v1   = (u32)f2b(aq[8]) | ((u32)f2b(aq[9]) << 16);
  *(uint4*)qr = v0;
  qr[4] = v1;
}

// ---- bucketing body: chunk-sort edges by bucket id (782 buckets), write
// the sorted chunk CONTIGUOUSLY to rec[bid*CHUNK_C..] + segt row.
// Record: ((dst & 127) << 17) | src   (src < 2^17)
__device__ __forceinline__ void coarse_body(
    int bid, int tid,
    const int* __restrict__ src, const int* __restrict__ dst,
    u32* __restrict__ rec, u32* __restrict__ segt)
{
  __shared__ u32 srt[CHUNK_C];        // 32 KB: chunk sorted by bucket id
  __shared__ u32 segst[NCB + 1];      // 3.1 KB: local exclusive scan
  __shared__ u32 rank[NCB];           // 3.1 KB: hist, then scatter rank
  __shared__ u32 wtot[4];

  for (int t = tid; t < NCB; t += FRONT_T) rank[t] = 0u;
  __syncthreads();

  int base = bid * CHUNK_C;
  const int4* __restrict__ dst4 = (const int4*)dst;
  const int4* __restrict__ src4 = (const int4*)src;
  // pass 1: histogram (int4 loads: 4 edges/thread/iter, 4 indep atomics)
  #pragma unroll
  for (int it = 0; it < CHUNK_C / (FRONT_T * 4); ++it) {
    int e = base + it * (FRONT_T * 4) + tid * 4;
    if (e < N_EDGES) {     // N_EDGES % 4 == 0, e % 4 == 0 -> whole int4 ok
      int4 d = dst4[(base >> 2) + it * FRONT_T + tid];
      atomicAdd(&rank[(u32)d.x >> SHIFTC], 1u);
      atomicAdd(&rank[(u32)d.y >> SHIFTC], 1u);
      atomicAdd(&rank[(u32)d.z >> SHIFTC], 1u);
      atomicAdd(&rank[(u32)d.w >> SHIFTC], 1u);
    }
  }
  __syncthreads();

  // exclusive scan of 782 bins: threads 0..195 hold 4 bins each; the wave
  // scan runs on waves 0..3 only (tid<256 guard -> wtot[4] stays in range).
  if (tid < 256) {
    u32 lh[4] = {0u, 0u, 0u, 0u};
    u32 lsum = 0u;
    if (tid < 196) {
      #pragma unroll
      for (int k = 0; k < 4; ++k) {
        int b4 = tid * 4 + k;
        lh[k] = (b4 < NCB) ? rank[b4] : 0u;
        lsum += lh[k];
      }
    }
    u32 v = lsum;
    #pragma unroll
    for (int off = 1; off < 64; off <<= 1) {
      u32 t = __shfl_up(v, off, 64);
      if ((tid & 63) >= off) v += t;
    }
    if ((tid & 63) == 63) wtot[tid >> 6] = v;
    __syncthreads();
    u32 wofs = 0u;
    #pragma unroll
    for (int w = 0; w < 3; ++w) if ((tid >> 6) > w) wofs += wtot[w];
    if (tid < 196) {
      u32 excl = wofs + v - lsum;    // exclusive prefix across threads
      #pragma unroll
      for (int k = 0; k < 4; ++k) {
        int b4 = tid * 4 + k;
        if (b4 < NCB) segst[b4] = excl;
        excl += lh[k];
      }
      if (tid == 195) segst[NCB] = excl;   // chunk total
    }
  } else {
    __syncthreads();                 // match the barrier inside the guard
  }
  __syncthreads();

  // reset rank for the scatter pass (no global reservation needed)
  for (int t = tid; t < NCB; t += FRONT_T) rank[t] = 0u;
  __syncthreads();

  // pass 2: scatter into LDS (sorted by bucket id)
  #pragma unroll
  for (int it = 0; it < CHUNK_C / (FRONT_T * 4); ++it) {
    int e = base + it * (FRONT_T * 4) + tid * 4;
    if (e < N_EDGES) {
      int4 d = dst4[(base >> 2) + it * FRONT_T + tid];
      int4 s = src4[(base >> 2) + it * FRONT_T + tid];
      #pragma unroll
      for (int q = 0; q < 4; ++q) {
        u32 dd = (u32)((q == 0) ? d.x : (q == 1) ? d.y : (q == 2) ? d.z : d.w);
        u32 ss = (u32)((q == 0) ? s.x : (q == 1) ? s.y : (q == 2) ? s.z : s.w);
        u32 cb = dd >> SHIFTC;
        u32 pos = segst[cb] + atomicAdd(&rank[cb], 1u);
        srt[pos] = ((dd & (NBINS - 1u)) << 17) | ss;   // pos < CHUNK_C always
      }
    }
  }
  __syncthreads();

  // write segment table row (783 contiguous u32) + sorted chunk (coalesced)
  for (int k = tid; k <= NCB; k += FRONT_T)
    segt[(size_t)bid * TW + k] = segst[k];
  int total = (int)segst[NCB];
  for (int t = tid; t < total; t += FRONT_T)
    rec[base + t] = srt[t];
}

// Fused front: blocks [0,NBLK_C) bucket edges, [NBLK_C,+NBLK_N) run gemm1.
__global__ __launch_bounds__(FRONT_T) void k_front(
    const int* __restrict__ src, const int* __restrict__ dst,
    u32* __restrict__ rec, u32* __restrict__ segt,
    const float* __restrict__ x, const float* __restrict__ W,
    float* __restrict__ p1, u16* __restrict__ q1b)
{
  if (blockIdx.x < NBLK_C)
    coarse_body(blockIdx.x, threadIdx.x, src, dst, rec, segt);
  else
    gemm_body(blockIdx.x - NBLK_C, threadIdx.x, x, W, p1, q1b);
}

// Segment gather: assumes srt (LDS sorted src), st, en, l in scope.
// Produces s[DIM] = 8-lane-reduced partial sums.
#define SEG_GATHER(QSRC)                                                      \
  float s[DIM];                                                               \
  _Pragma("unroll")                                                           \
  for (int j = 0; j < DIM; ++j) s[j] = 0.f;                                   \
  {                                                                           \
    int k = st + l;                                                           \
    for (; k + 8 < en; k += 16) {                                             \
      int s0 = (int)srt[k], s1 = (int)srt[k + 8];                             \
      const u32* __restrict__ q0 = (const u32*)(QSRC + (size_t)s0 * QB);      \
      const u32* __restrict__ q1 = (const u32*)(QSRC + (size_t)s1 * QB);      \
      uint4 A0 = *(const uint4*)q0; u32 B0 = q0[4];                           \
      uint4 A1 = *(const uint4*)q1; u32 B1 = q1[4];                           \
      s[0] += bl(A0.x) + bl(A1.x); s[1] += bh(A0.x) + bh(A1.x);               \
      s[2] += bl(A0.y) + bl(A1.y); s[3] += bh(A0.y) + bh(A1.y);               \
      s[4] += bl(A0.z) + bl(A1.z); s[5] += bh(A0.z) + bh(A1.z);               \
      s[6] += bl(A0.w) + bl(A1.w); s[7] += bh(A0.w) + bh(A1.w);               \
      s[8] += bl(B0) + bl(B1);     s[9] += bh(B0) + bh(B1);                   \
    }                                                                         \
    if (k < en) {                                                             \
      int s0 = (int)srt[k];                                                   \
      const u32* __restrict__ q0 = (const u32*)(QSRC + (size_t)s0 * QB);      \
      uint4 A0 = *(const uint4*)q0; u32 B0 = q0[4];                           \
      s[0] += bl(A0.x); s[1] += bh(A0.x);                                     \
      s[2] += bl(A0.y); s[3] += bh(A0.y);                                     \
      s[4] += bl(A0.z); s[5] += bh(A0.z);                                     \
      s[6] += bl(A0.w); s[7] += bh(A0.w);                                     \
      s[8] += bl(B0);   s[9] += bh(B0);                                       \
    }                                                                         \
  }                                                                           \
  _Pragma("unroll")                                                           \
  for (int m = 1; m < 8; m <<= 1) {                                           \
    _Pragma("unroll")                                                         \
    for (int j = 0; j < DIM; ++j) s[j] += __shfl_xor(s[j], m, 8);             \
  }

// Layer 1: assemble bucket c from the 391 per-chunk runs. Pass A:
// histogram straight from the global runs (no LDS stage). Wave-scan the
// 128 bins. Pass B: re-read the runs (L1/L2-hot, ~16KB/block) and scatter
// directly into srt. Persist (sortrec+segg) for k_zpool, gather q1b,
// epilogue h = relu(p1+mean); y = h.wv1, z = h.wv2 (folded W2@Wfc).
// LDS 21.6KB -> 4 blocks/CU (was 40.4KB / 3).
__global__ __launch_bounds__(512) void k_lay1(
    const u32* __restrict__ rec, const u32* __restrict__ segt,
    const float* __restrict__ p1, const u16* __restrict__ q1b,
    const float* __restrict__ W2, const float* __restrict__ Wfc,
    float* __restrict__ y, float* __restrict__ z,
    u32* __restrict__ sortrec, u32* __restrict__ segg)
{
  __shared__ u32 srt[CAPC];           // 18 KB
  __shared__ u32 hist[NBINS];
  __shared__ u32 segst[NBINS + 1];
  __shared__ u32 rank[NBINS];
  __shared__ u32 wtot[2];
  __shared__ u32 cwtot[4];
  __shared__ u32 bst[NBLK_C];         // per-chunk base within bucket
  __shared__ u32 ntot_s;
  __shared__ float wv[2 * DIM];       // wv[k] = sum_j W2[k][j] * Wfc[j]
  int tid = threadIdx.x;
  int c = blockIdx.x;
  if (tid < 2 * DIM) {
    float sacc = 0.f;
    #pragma unroll
    for (int j = 0; j < DIM; ++j) sacc += W2[tid * DIM + j] * Wfc[j];
    wv[tid] = sacc;
  }
  if (tid < NBINS) { hist[tid] = 0u; rank[tid] = 0u; }

  // exclusive scan of the 391 per-chunk counts: threads 0..97 hold 4 each,
  // wave scan on waves 0..3 (tid<256 guard), 2 barriers total.
  if (tid < 256) {
    u32 lh[4] = {0u, 0u, 0u, 0u};
    u32 lsum = 0u;
    if (tid < 98) {
      #pragma unroll
      for (int k = 0; k < 4; ++k) {
        int b4 = tid * 4 + k;
        if (b4 < NBLK_C) {
          lh[k] = segt[(size_t)b4 * TW + c + 1] - segt[(size_t)b4 * TW + c];
          lsum += lh[k];
        }
      }
    }
    u32 v = lsum;
    #pragma unroll
    for (int off = 1; off < 64; off <<= 1) {
      u32 t = __shfl_up(v, off, 64);
      if ((tid & 63) >= off) v += t;
    }
    if ((tid & 63) == 63) cwtot[tid >> 6] = v;
    __syncthreads();
    u32 wofs = 0u;
    #pragma unroll
    for (int w = 0; w < 3; ++w) if ((tid >> 6) > w) wofs += cwtot[w];
    if (tid < 98) {
      u32 excl = wofs + v - lsum;
      #pragma unroll
      for (int k = 0; k < 4; ++k) {
        int b4 = tid * 4 + k;
        if (b4 < NBLK_C) { bst[b4] = excl; excl += lh[k]; }
      }
      if (tid == 97) ntot_s = excl;  // bucket total
    }
  } else {
    __syncthreads();                 // match the barrier inside the guard
  }
  __syncthreads();
  int n = min((int)ntot_s, CAPC);
  int grp = tid >> 3, l = tid & 7;   // 64 groups of 8 lanes

  // pass A: histogram straight from the global runs
  for (int b = grp; b < NBLK_C; b += 64) {
    u32 s0 = segt[(size_t)b * TW + c];
    u32 cn = segt[(size_t)b * TW + c + 1] - s0;
    const u32* __restrict__ rp = rec + (size_t)b * CHUNK_C + s0;
    for (u32 r = l; r < cn; r += 8u)
      atomicAdd(&hist[(rp[r] >> 17) & (NBINS - 1u)], 1u);
  }
  __syncthreads();
  // 128-bin exclusive scan: intra-wave shfl scan + cross-wave offset
  if (tid < NBINS) {
    u32 h = hist[tid];
    u32 v = h;
    #pragma unroll
    for (int off = 1; off < 64; off <<= 1) {
      u32 t = __shfl_up(v, off, 64);
      if ((tid & 63) >= off) v += t;
    }
    if ((tid & 63) == 63) wtot[tid >> 6] = v;
    segst[tid] = v - h;
  }
  __syncthreads();
  if (tid >= 64 && tid < NBINS) segst[tid] += wtot[0];
  if (tid == 0) segst[NBINS] = wtot[0] + wtot[1];
  __syncthreads();
  // pass B: re-read runs (cache-hot) and scatter into srt (sorted by bin)
  for (int b = grp; b < NBLK_C; b += 64) {
    u32 s0 = segt[(size_t)b * TW + c];
    u32 cn = segt[(size_t)b * TW + c + 1] - s0;
    const u32* __restrict__ rp = rec + (size_t)b * CHUNK_C + s0;
    for (u32 r = l; r < cn; r += 8u) {
      u32 v = rp[r];
      u32 dl = (v >> 17) & (NBINS - 1u);
      u32 pos = segst[dl] + atomicAdd(&rank[dl], 1u);
      if (pos < (u32)CAPC)           // memory-safety only
        srt[pos] = v & 0x1FFFFu;
    }
  }
  __syncthreads();
  // persist sorted order + segment table (k_zpool streams them)
  for (int r = tid; r < n; r += 512) sortrec[(size_t)c * CAPC + r] = srt[r];
  if (tid <= NBINS) segg[(size_t)c * SEGW + tid] = segst[tid];
  // gather + epilogue: 64 groups of 8 lanes, 2 rounds cover 128 nodes
  int g0 = grp;
  #pragma unroll
  for (int rd = 0; rd < 2; ++rd) {
    int g2 = rd * 64 + g0;
    int st = (int)segst[g2], en = (int)segst[g2 + 1];
    SEG_GATHER(q1b)
    if (l == 0) {
      int i = c * NBINS + g2;
      if (i < N_NODES) {
        float dinv = 1.0f / fmaxf((float)(en - st), 1.0f);
        const float* __restrict__ pr = p1 + (size_t)i * DIM;
        float yv = 0.f, zv = 0.f;
        #pragma unroll
        for (int j = 0; j < DIM; ++j) {
          float h = fmaxf(pr[j] + s[j] * dinv, 0.0f);
          yv += h * wv[j];
          zv += h * wv[DIM + j];
        }
        y[i] = yv;
        z[i] = zv;
      }
    }
  }
}

// Merged layer2+pool: one block per graph. For each node in the graph's
// contiguous range, stream its persisted sorted segment (segg lookup),
// gather z[src] (4B, L2-resident 400KB table), val = y + mean(z-seg);
// block-reduce, sigmoid -> out[g]. Zero atomics, no LDS staging.
__global__ __launch_bounds__(256) void k_zpool(
    const u32* __restrict__ sortrec, const u32* __restrict__ segg,
    const float* __restrict__ y, const float* __restrict__ z,
    const int* __restrict__ batch, float* __restrict__ out)
{
  __shared__ float wsum[4];
  int g = blockIdx.x;
  int tid = threadIdx.x;
  int lo = 0, hi = N_NODES;
  while (lo < hi) { int m = (lo + hi) >> 1; if (batch[m] < g) lo = m + 1; else hi = m; }
  int start = lo;
  hi = N_NODES;
  while (lo < hi) { int m = (lo + hi) >> 1; if (batch[m] < g + 1) lo = m + 1; else hi = m; }
  int end = lo;
  int grp = tid >> 3, l = tid & 7;    // 32 groups of 8 lanes
  float acc = 0.f;
  for (int i = start + grp; i < end; i += 32) {
    int c = i >> SHIFTC, bin = i & (NBINS - 1);
    u32 st = segg[(size_t)c * SEGW + bin];
    u32 en = segg[(size_t)c * SEGW + bin + 1];
    const u32* __restrict__ rc = sortrec + (size_t)c * CAPC;
    float sc = 0.f;
    for (u32 k = st + l; k < en; k += 8u) sc += z[rc[k]];
    #pragma unroll
    for (int m = 1; m < 8; m <<= 1) sc += __shfl_xor(sc, m, 8);
    if (l == 0) acc += y[i] + sc / fmaxf((float)(en - st), 1.0f);
  }
  // block reduction (non-l0 lanes hold 0 after masking)
  if (l != 0) acc = 0.f;
  #pragma unroll
  for (int m = 1; m < 64; m <<= 1) acc += __shfl_xor(acc, m, 64);
  if ((tid & 63) == 0) wsum[tid >> 6] = acc;
  __syncthreads();
  if (tid == 0) {
    float tot = wsum[0] + wsum[1] + wsum[2] + wsum[3];
    float gm = tot / fmaxf((float)(end - start), 1.0f);
    out[g] = 1.0f / (1.0f + expf(-gm));
  }
}

extern "C" void kernel_launch(void* const* d_in, const int* in_sizes, int n_in,
                              void* d_out, int out_size, void* d_ws, size_t ws_size,
                              hipStream_t stream)
{
  const float* x     = (const float*)d_in[0];
  const int*   ei    = (const int*)d_in[1];
  const int*   batch = (const int*)d_in[2];
  const float* W1    = (const float*)d_in[3];
  const float* W2    = (const float*)d_in[4];
  const float* Wfc   = (const float*)d_in[5];
  float* out = (float*)d_out;

  const int* src = ei;            // edge_index[0]
  const int* dst = ei + N_EDGES;  // edge_index[1]

  // ---- workspace layout (u32 element offsets), total ~36.9 MB.
  // NOTHING needs zero-init: segt fully written by front, sortrec/segg by
  // lay1, y/z by lay1 -> no memset dispatch.
  u32* wsp = (u32*)d_ws;
  u32* rec     = wsp;                                 // 391*8192 = 3,203,072
  u32* segt    = rec + (size_t)NBLK_C * CHUNK_C;      // 391*783 (pad 306,176)
  u32* sortrec = segt + 306176;                       // 782*4608 = 3,603,456
  u32* segg    = sortrec + (size_t)NCB * CAPC;        // 782*129 (pad 100,928)
  u32* after   = segg + 100928;
  u16*   q1b = (u16*)after;                           // 800,000 u32
  float* p1  = (float*)(after + 800000);              // 1,000,000 u32
  float* y   = (float*)(after + 1800000);             // 100,096 u32
  float* z   = (float*)(after + 1900096);             // 100,096 u32

  k_front<<<NBLK_C + NBLK_N, FRONT_T, 0, stream>>>(src, dst, rec, segt,
                                                   x, W1, p1, q1b);
  k_lay1<<<NCB, 512, 0, stream>>>(rec, segt, p1, q1b, W2, Wfc, y, z,
                                  sortrec, segg);
  k_zpool<<<B_GRAPHS, 256, 0, stream>>>(sortrec, segg, y, z, batch, out);
}

// Round 15
// 186.488 us; speedup vs baseline: 1.0404x; 1.0404x over previous
//
#include <hip/hip_runtime.h>
#include <cstdint>

typedef unsigned int u32;
typedef unsigned short u16;

#define N_NODES 100000
#define N_EDGES 3200000
#define F_IN 128
#define DIM 10
#define QB 16            // bf16 elems per padded q row -> 32B
#define B_GRAPHS 1000
#define FRONT_T 512      // threads per k_front block (r11-proven)
#define NBLK_N 196       // ceil(N/512) gemm blocks

// r15 = r13 (183.0us best) + r14's 2-barrier count scan ONLY.
// r14's lrec-less lay1 REVERTED: the run re-read was not cache-hot
// (FETCH 46.5->75.7MB, +15us). LDS staging of line-amplified scattered
// reads is worth 3-vs-4 blocks/CU.
#define SHIFTC 7
#define NBINS 128        // dst & 127 within a bucket
#define NCB 782          // ceil(N/128)
#define CAPC 4608        // slots/bucket: mean 4092 + 8 sigma
#define CHUNK_C 8192     // edges per bucketing block
#define NBLK_C 391       // ceil(E/CHUNK_C)
#define SEGW 129         // segment-start words per bucket (NBINS+1)
#define TW (NCB + 1)     // segt row width (783)

__device__ __forceinline__ u16 f2b(float f) {           // f32 -> bf16 (RNE)
  union { float f; u32 i; } c; c.f = f;
  u32 r = c.i + 0x7FFFu + ((c.i >> 16) & 1u);
  return (u16)(r >> 16);
}
__device__ __forceinline__ float bl(u32 u) {            // low bf16 -> f32
  union { u32 i; float f; } c; c.i = u << 16; return c.f;
}
__device__ __forceinline__ float bh(u32 u) {            // high bf16 -> f32
  union { u32 i; float f; } c; c.i = u & 0xFFFF0000u; return c.f;
}

// ---- gemm1 body: 1 thread/node (512/block), wave-uniform W indexing ----
__device__ __forceinline__ void gemm_body(
    int bid, int tid,
    const float* __restrict__ x, const float* __restrict__ W,
    float* __restrict__ p1, u16* __restrict__ q1b)
{
  int i = bid * FRONT_T + tid;
  if (i >= N_NODES) return;
  const float4* __restrict__ xr = (const float4*)(x + (size_t)i * F_IN);
  float ap[DIM], aq[DIM];
  #pragma unroll
  for (int j = 0; j < DIM; ++j) { ap[j] = 0.f; aq[j] = 0.f; }
  #pragma unroll 4
  for (int k4 = 0; k4 < F_IN / 4; ++k4) {
    float4 v = xr[k4];
    const float* __restrict__ w0 = W + (k4 * 4) * DIM;
    const float* __restrict__ w1 = W + (F_IN + k4 * 4) * DIM;
    #pragma unroll
    for (int j = 0; j < DIM; ++j) {
      ap[j] += v.x * w0[j] + v.y * w0[DIM + j] + v.z * w0[2 * DIM + j] + v.w * w0[3 * DIM + j];
      aq[j] += v.x * w1[j] + v.y * w1[DIM + j] + v.z * w1[2 * DIM + j] + v.w * w1[3 * DIM + j];
    }
  }
  float* pr = p1 + (size_t)i * DIM;
  #pragma unroll
  for (int j = 0; j < DIM; ++j) pr[j] = ap[j];
  u32* qr = (u32*)(q1b + (size_t)i * QB);
  uint4 v0; u32 v1;
  v0.x = (u32)f2b(aq[0]) | ((u32)f2b(aq[1]) << 16);
  v0.y = (u32)f2b(aq[2]) | ((u32)f2b(aq[3]) << 16);
  v0.z = (u32)f2b(aq[4]) | ((u32)f2b(aq[5]) << 16);
  v0.w = (u32)f2b(aq[6]) | ((u32)f2b(aq[7]) << 16);
  v1   = (u32)f2b(aq[8]) | ((u32)f2b(aq[9]) << 16);
  *(uint4*)qr = v0;
  qr[4] = v1;
}

// ---- bucketing body: chunk-sort edges by bucket id (782 buckets), write
// the sorted chunk CONTIGUOUSLY to rec[bid*CHUNK_C..] + segt row.
// Record: ((dst & 127) << 17) | src   (src < 2^17)
__device__ __forceinline__ void coarse_body(
    int bid, int tid,
    const int* __restrict__ src, const int* __restrict__ dst,
    u32* __restrict__ rec, u32* __restrict__ segt)
{
  __shared__ u32 srt[CHUNK_C];        // 32 KB: chunk sorted by bucket id
  __shared__ u32 segst[NCB + 1];      // 3.1 KB: local exclusive scan
  __shared__ u32 rank[NCB];           // 3.1 KB: hist, then scatter rank
  __shared__ u32 wtot[4];

  for (int t = tid; t < NCB; t += FRONT_T) rank[t] = 0u;
  __syncthreads();

  int base = bid * CHUNK_C;
  const int4* __restrict__ dst4 = (const int4*)dst;
  const int4* __restrict__ src4 = (const int4*)src;
  // pass 1: histogram (int4 loads: 4 edges/thread/iter, 4 indep atomics)
  #pragma unroll
  for (int it = 0; it < CHUNK_C / (FRONT_T * 4); ++it) {
    int e = base + it * (FRONT_T * 4) + tid * 4;
    if (e < N_EDGES) {     // N_EDGES % 4 == 0, e % 4 == 0 -> whole int4 ok
      int4 d = dst4[(base >> 2) + it * FRONT_T + tid];
      atomicAdd(&rank[(u32)d.x >> SHIFTC], 1u);
      atomicAdd(&rank[(u32)d.y >> SHIFTC], 1u);
      atomicAdd(&rank[(u32)d.z >> SHIFTC], 1u);
      atomicAdd(&rank[(u32)d.w >> SHIFTC], 1u);
    }
  }
  __syncthreads();

  // exclusive scan of 782 bins: threads 0..195 hold 4 bins each; the wave
  // scan runs on waves 0..3 only (tid<256 guard -> wtot[4] stays in range).
  if (tid < 256) {
    u32 lh[4] = {0u, 0u, 0u, 0u};
    u32 lsum = 0u;
    if (tid < 196) {
      #pragma unroll
      for (int k = 0; k < 4; ++k) {
        int b4 = tid * 4 + k;
        lh[k] = (b4 < NCB) ? rank[b4] : 0u;
        lsum += lh[k];
      }
    }
    u32 v = lsum;
    #pragma unroll
    for (int off = 1; off < 64; off <<= 1) {
      u32 t = __shfl_up(v, off, 64);
      if ((tid & 63) >= off) v += t;
    }
    if ((tid & 63) == 63) wtot[tid >> 6] = v;
    __syncthreads();
    u32 wofs = 0u;
    #pragma unroll
    for (int w = 0; w < 3; ++w) if ((tid >> 6) > w) wofs += wtot[w];
    if (tid < 196) {
      u32 excl = wofs + v - lsum;    // exclusive prefix across threads
      #pragma unroll
      for (int k = 0; k < 4; ++k) {
        int b4 = tid * 4 + k;
        if (b4 < NCB) segst[b4] = excl;
        excl += lh[k];
      }
      if (tid == 195) segst[NCB] = excl;   // chunk total
    }
  } else {
    __syncthreads();                 // match the barrier inside the guard
  }
  __syncthreads();

  // reset rank for the scatter pass (no global reservation needed)
  for (int t = tid; t < NCB; t += FRONT_T) rank[t] = 0u;
  __syncthreads();

  // pass 2: scatter into LDS (sorted by bucket id)
  #pragma unroll
  for (int it = 0; it < CHUNK_C / (FRONT_T * 4); ++it) {
    int e = base + it * (FRONT_T * 4) + tid * 4;
    if (e < N_EDGES) {
      int4 d = dst4[(base >> 2) + it * FRONT_T + tid];
      int4 s = src4[(base >> 2) + it * FRONT_T + tid];
      #pragma unroll
      for (int q = 0; q < 4; ++q) {
        u32 dd = (u32)((q == 0) ? d.x : (q == 1) ? d.y : (q == 2) ? d.z : d.w);
        u32 ss = (u32)((q == 0) ? s.x : (q == 1) ? s.y : (q == 2) ? s.z : s.w);
        u32 cb = dd >> SHIFTC;
        u32 pos = segst[cb] + atomicAdd(&rank[cb], 1u);
        srt[pos] = ((dd & (NBINS - 1u)) << 17) | ss;   // pos < CHUNK_C always
      }
    }
  }
  __syncthreads();

  // write segment table row (783 contiguous u32) + sorted chunk (coalesced)
  for (int k = tid; k <= NCB; k += FRONT_T)
    segt[(size_t)bid * TW + k] = segst[k];
  int total = (int)segst[NCB];
  for (int t = tid; t < total; t += FRONT_T)
    rec[base + t] = srt[t];
}

// Fused front: blocks [0,NBLK_C) bucket edges, [NBLK_C,+NBLK_N) run gemm1.
__global__ __launch_bounds__(FRONT_T) void k_front(
    const int* __restrict__ src, const int* __restrict__ dst,
    u32* __restrict__ rec, u32* __restrict__ segt,
    const float* __restrict__ x, const float* __restrict__ W,
    float* __restrict__ p1, u16* __restrict__ q1b)
{
  if (blockIdx.x < NBLK_C)
    coarse_body(blockIdx.x, threadIdx.x, src, dst, rec, segt);
  else
    gemm_body(blockIdx.x - NBLK_C, threadIdx.x, x, W, p1, q1b);
}

// Segment gather: assumes srt (LDS sorted src), st, en, l in scope.
// Produces s[DIM] = 8-lane-reduced partial sums.
#define SEG_GATHER(QSRC)                                                      \
  float s[DIM];                                                               \
  _Pragma("unroll")                                                           \
  for (int j = 0; j < DIM; ++j) s[j] = 0.f;                                   \
  {                                                                           \
    int k = st + l;                                                           \
    for (; k + 8 < en; k += 16) {                                             \
      int s0 = (int)srt[k], s1 = (int)srt[k + 8];                             \
      const u32* __restrict__ q0 = (const u32*)(QSRC + (size_t)s0 * QB);      \
      const u32* __restrict__ q1 = (const u32*)(QSRC + (size_t)s1 * QB);      \
      uint4 A0 = *(const uint4*)q0; u32 B0 = q0[4];                           \
      uint4 A1 = *(const uint4*)q1; u32 B1 = q1[4];                           \
      s[0] += bl(A0.x) + bl(A1.x); s[1] += bh(A0.x) + bh(A1.x);               \
      s[2] += bl(A0.y) + bl(A1.y); s[3] += bh(A0.y) + bh(A1.y);               \
      s[4] += bl(A0.z) + bl(A1.z); s[5] += bh(A0.z) + bh(A1.z);               \
      s[6] += bl(A0.w) + bl(A1.w); s[7] += bh(A0.w) + bh(A1.w);               \
      s[8] += bl(B0) + bl(B1);     s[9] += bh(B0) + bh(B1);                   \
    }                                                                         \
    if (k < en) {                                                             \
      int s0 = (int)srt[k];                                                   \
      const u32* __restrict__ q0 = (const u32*)(QSRC + (size_t)s0 * QB);      \
      uint4 A0 = *(const uint4*)q0; u32 B0 = q0[4];                           \
      s[0] += bl(A0.x); s[1] += bh(A0.x);                                     \
      s[2] += bl(A0.y); s[3] += bh(A0.y);                                     \
      s[4] += bl(A0.z); s[5] += bh(A0.z);                                     \
      s[6] += bl(A0.w); s[7] += bh(A0.w);                                     \
      s[8] += bl(B0);   s[9] += bh(B0);                                       \
    }                                                                         \
  }                                                                           \
  _Pragma("unroll")                                                           \
  for (int m = 1; m < 8; m <<= 1) {                                           \
    _Pragma("unroll")                                                         \
    for (int j = 0; j < DIM; ++j) s[j] += __shfl_xor(s[j], m, 8);             \
  }

// Layer 1: assemble bucket c from the 391 per-chunk runs (2-barrier wave
// scan of counts + SINGLE global pass: gather runs into lrec + histogram),
// counting-sort by dst-low in LDS, persist sorted order (sortrec + segg)
// for k_zpool, gather q1b, epilogue h = relu(p1+mean);
// y = h.wv1, z = h.wv2 (folded W2@Wfc).
__global__ __launch_bounds__(512) void k_lay1(
    const u32* __restrict__ rec, const u32* __restrict__ segt,
    const float* __restrict__ p1, const u16* __restrict__ q1b,
    const float* __restrict__ W2, const float* __restrict__ Wfc,
    float* __restrict__ y, float* __restrict__ z,
    u32* __restrict__ sortrec, u32* __restrict__ segg)
{
  __shared__ u32 lrec[CAPC];          // 18 KB (staged records)
  __shared__ u32 srt[CAPC];           // 18 KB (sorted srcs)
  __shared__ u32 hist[NBINS];
  __shared__ u32 segst[NBINS + 1];
  __shared__ u32 rank[NBINS];
  __shared__ u32 wtot[2];
  __shared__ u32 cwtot[4];
  __shared__ u32 bst[NBLK_C];         // per-chunk base within bucket
  __shared__ u32 ntot_s;
  __shared__ float wv[2 * DIM];       // wv[k] = sum_j W2[k][j] * Wfc[j]
  int tid = threadIdx.x;
  int c = blockIdx.x;
  if (tid < 2 * DIM) {
    float sacc = 0.f;
    #pragma unroll
    for (int j = 0; j < DIM; ++j) sacc += W2[tid * DIM + j] * Wfc[j];
    wv[tid] = sacc;
  }
  if (tid < NBINS) { hist[tid] = 0u; rank[tid] = 0u; }

  // exclusive scan of the 391 per-chunk counts: threads 0..97 hold 4 each,
  // wave scan on waves 0..3 (tid<256 guard), 2 barriers total.
  if (tid < 256) {
    u32 lh[4] = {0u, 0u, 0u, 0u};
    u32 lsum = 0u;
    if (tid < 98) {
      #pragma unroll
      for (int k = 0; k < 4; ++k) {
        int b4 = tid * 4 + k;
        if (b4 < NBLK_C) {
          lh[k] = segt[(size_t)b4 * TW + c + 1] - segt[(size_t)b4 * TW + c];
          lsum += lh[k];
        }
      }
    }
    u32 v = lsum;
    #pragma unroll
    for (int off = 1; off < 64; off <<= 1) {
      u32 t = __shfl_up(v, off, 64);
      if ((tid & 63) >= off) v += t;
    }
    if ((tid & 63) == 63) cwtot[tid >> 6] = v;
    __syncthreads();
    u32 wofs = 0u;
    #pragma unroll
    for (int w = 0; w < 3; ++w) if ((tid >> 6) > w) wofs += cwtot[w];
    if (tid < 98) {
      u32 excl = wofs + v - lsum;
      #pragma unroll
      for (int k = 0; k < 4; ++k) {
        int b4 = tid * 4 + k;
        if (b4 < NBLK_C) { bst[b4] = excl; excl += lh[k]; }
      }
      if (tid == 97) ntot_s = excl;  // bucket total
    }
  } else {
    __syncthreads();                 // match the barrier inside the guard
  }
  __syncthreads();
  int n = min((int)ntot_s, CAPC);
  int grp = tid >> 3, l = tid & 7;   // 64 groups of 8 lanes

  // SINGLE global pass: gather the 391 runs into lrec (+histogram)
  for (int b = grp; b < NBLK_C; b += 64) {
    u32 s0 = segt[(size_t)b * TW + c];
    u32 cn = segt[(size_t)b * TW + c + 1] - s0;
    const u32* __restrict__ rp = rec + (size_t)b * CHUNK_C + s0;
    u32 bb = bst[b];
    for (u32 r = l; r < cn; r += 8u) {
      u32 pos = bb + r;
      if (pos < (u32)CAPC) {
        u32 v = rp[r];
        lrec[pos] = v;
        atomicAdd(&hist[(v >> 17) & (NBINS - 1u)], 1u);
      }
    }
  }
  __syncthreads();
  // 128-bin exclusive scan: intra-wave shfl scan + cross-wave offset
  if (tid < NBINS) {
    u32 h = hist[tid];
    u32 v = h;
    #pragma unroll
    for (int off = 1; off < 64; off <<= 1) {
      u32 t = __shfl_up(v, off, 64);
      if ((tid & 63) >= off) v += t;
    }
    if ((tid & 63) == 63) wtot[tid >> 6] = v;
    segst[tid] = v - h;
  }
  __syncthreads();
  if (tid >= 64 && tid < NBINS) segst[tid] += wtot[0];
  if (tid == 0) segst[NBINS] = wtot[0] + wtot[1];
  __syncthreads();
  // scatter from lrec into srt (sorted by bin)
  for (int r = tid; r < n; r += 512) {
    u32 v = lrec[r];
    u32 dl = (v >> 17) & (NBINS - 1u);
    u32 pos = segst[dl] + atomicAdd(&rank[dl], 1u);
    srt[pos] = v & 0x1FFFFu;
  }
  __syncthreads();
  // persist sorted order + segment table (k_zpool streams them)
  for (int r = tid; r < n; r += 512) sortrec[(size_t)c * CAPC + r] = srt[r];
  if (tid <= NBINS) segg[(size_t)c * SEGW + tid] = segst[tid];
  // gather + epilogue: 64 groups of 8 lanes, 2 rounds cover 128 nodes
  #pragma unroll
  for (int rd = 0; rd < 2; ++rd) {
    int g2 = rd * 64 + grp;
    int st = (int)segst[g2], en = (int)segst[g2 + 1];
    SEG_GATHER(q1b)
    if (l == 0) {
      int i = c * NBINS + g2;
      if (i < N_NODES) {
        float dinv = 1.0f / fmaxf((float)(en - st), 1.0f);
        const float* __restrict__ pr = p1 + (size_t)i * DIM;
        float yv = 0.f, zv = 0.f;
        #pragma unroll
        for (int j = 0; j < DIM; ++j) {
          float h = fmaxf(pr[j] + s[j] * dinv, 0.0f);
          yv += h * wv[j];
          zv += h * wv[DIM + j];
        }
        y[i] = yv;
        z[i] = zv;
      }
    }
  }
}

// Merged layer2+pool: one block per graph. For each node in the graph's
// contiguous range, stream its persisted sorted segment (segg lookup),
// gather z[src] (4B, L2-resident 400KB table), val = y + mean(z-seg);
// block-reduce, sigmoid -> out[g]. Zero atomics, no LDS staging.
__global__ __launch_bounds__(256) void k_zpool(
    const u32* __restrict__ sortrec, const u32* __restrict__ segg,
    const float* __restrict__ y, const float* __restrict__ z,
    const int* __restrict__ batch, float* __restrict__ out)
{
  __shared__ float wsum[4];
  int g = blockIdx.x;
  int tid = threadIdx.x;
  int lo = 0, hi = N_NODES;
  while (lo < hi) { int m = (lo + hi) >> 1; if (batch[m] < g) lo = m + 1; else hi = m; }
  int start = lo;
  hi = N_NODES;
  while (lo < hi) { int m = (lo + hi) >> 1; if (batch[m] < g + 1) lo = m + 1; else hi = m; }
  int end = lo;
  int grp = tid >> 3, l = tid & 7;    // 32 groups of 8 lanes
  float acc = 0.f;
  for (int i = start + grp; i < end; i += 32) {
    int c = i >> SHIFTC, bin = i & (NBINS - 1);
    u32 st = segg[(size_t)c * SEGW + bin];
    u32 en = segg[(size_t)c * SEGW + bin + 1];
    const u32* __restrict__ rc = sortrec + (size_t)c * CAPC;
    float sc = 0.f;
    for (u32 k = st + l; k < en; k += 8u) sc += z[rc[k]];
    #pragma unroll
    for (int m = 1; m < 8; m <<= 1) sc += __shfl_xor(sc, m, 8);
    if (l == 0) acc += y[i] + sc / fmaxf((float)(en - st), 1.0f);
  }
  // block reduction (non-l0 lanes hold 0 after masking)
  if (l != 0) acc = 0.f;
  #pragma unroll
  for (int m = 1; m < 64; m <<= 1) acc += __shfl_xor(acc, m, 64);
  if ((tid & 63) == 0) wsum[tid >> 6] = acc;
  __syncthreads();
  if (tid == 0) {
    float tot = wsum[0] + wsum[1] + wsum[2] + wsum[3];
    float gm = tot / fmaxf((float)(end - start), 1.0f);
    out[g] = 1.0f / (1.0f + expf(-gm));
  }
}

extern "C" void kernel_launch(void* const* d_in, const int* in_sizes, int n_in,
                              void* d_out, int out_size, void* d_ws, size_t ws_size,
                              hipStream_t stream)
{
  const float* x     = (const float*)d_in[0];
  const int*   ei    = (const int*)d_in[1];
  const int*   batch = (const int*)d_in[2];
  const float* W1    = (const float*)d_in[3];
  const float* W2    = (const float*)d_in[4];
  const float* Wfc   = (const float*)d_in[5];
  float* out = (float*)d_out;

  const int* src = ei;            // edge_index[0]
  const int* dst = ei + N_EDGES;  // edge_index[1]

  // ---- workspace layout (u32 element offsets), total ~36.9 MB.
  // NOTHING needs zero-init: segt fully written by front, sortrec/segg by
  // lay1, y/z by lay1 -> no memset dispatch.
  u32* wsp = (u32*)d_ws;
  u32* rec     = wsp;                                 // 391*8192 = 3,203,072
  u32* segt    = rec + (size_t)NBLK_C * CHUNK_C;      // 391*783 (pad 306,176)
  u32* sortrec = segt + 306176;                       // 782*4608 = 3,603,456
  u32* segg    = sortrec + (size_t)NCB * CAPC;        // 782*129 (pad 100,928)
  u32* after   = segg + 100928;
  u16*   q1b = (u16*)after;                           // 800,000 u32
  float* p1  = (float*)(after + 800000);              // 1,000,000 u32
  float* y   = (float*)(after + 1800000);             // 100,096 u32
  float* z   = (float*)(after + 1900096);             // 100,096 u32

  k_front<<<NBLK_C + NBLK_N, FRONT_T, 0, stream>>>(src, dst, rec, segt,
                                                   x, W1, p1, q1b);
  k_lay1<<<NCB, 512, 0, stream>>>(rec, segt, p1, q1b, W2, Wfc, y, z,
                                  sortrec, segg);
  k_zpool<<<B_GRAPHS, 256, 0, stream>>>(sortrec, segg, y, z, batch, out);
}